// Round 7
// baseline (112.249 us; speedup 1.0000x reference)
//
#include <hip/hip_runtime.h>
#include <math.h>

// CLUB_NCE: N=512, D=400, H=400.
// M0 : hipMemsetAsync zeroes hxT8+hyb (atomic accumulation targets).
// K1 : hidden GEMM, k-split 2 across grid (848 blocks, ~3 waves/SIMD).
//      Lane-dim operand staged in LDS, 4 wave-uniform scalar rows per thread
//      (s_load path). Both kh-halves atomicAdd into the same buffers —
//      exactly 2 addends per element => order-independent, bit-exact.
//      mat0 -> hxT8[h/8][j][h%8] (oct-interleaved), mat1 -> hyb[n][h] (+b1).
// K2 : pair scores. 1024 blocks (4 waves/SIMD), lane=j, wave=i. No LDS, no
//      barriers: B = 2 coalesced dwordx4 per 8-h group from hxT8, A/W2 via
//      uniform s_loads. Fused softplus + per-row fp64 wave reduction.
// K3 : fp64 logsumexp assembly -> (lower, upper).

#define NSAMP 512
#define DIM 400
#define HID 400

// ---------------- K1 ----------------
// blocks 0..399   : mat0: kh=b&1, bx=(b>>1)&7 -> j0=bx*64 (lane), by=b>>4 (0..24) -> h0=by*16
// blocks 400..847 : mat1: bb=b-400: kh=bb&1, bx=(bb>>1)&31 -> n0=bx*16, by=bb>>6 (0..6) -> h0=by*64 (lane)
__global__ __launch_bounds__(256) void club_gemm_kernel(
    const float* __restrict__ X, const float* __restrict__ Y,
    const float* __restrict__ W1, const float* __restrict__ b1,
    float* __restrict__ hxT8, float* __restrict__ hyb)
{
    __shared__ __align__(16) float Ls[64 * 204];   // 52224 B -> 3 blocks/CU
    const int t    = threadIdx.x;
    const int lane = t & 63;
    const int wave = __builtin_amdgcn_readfirstlane(t >> 6);
    const int b    = blockIdx.x;

    const float* __restrict__ Lbase;   // lane-dim matrix (LDS-staged)
    const float* __restrict__ Sbase;   // scalar-dim matrix (s_load)
    int Lstride, Lcol0, Lrow0, Lrowmax, Sstride, srow_base;
    int kh, mat;

    if (b < 400) {                    // mat0: hx
        mat = 0; kh = b & 1;
        const int bx = (b >> 1) & 7, by = b >> 4;
        Lbase = X;  Lstride = DIM;     Lcol0 = 0;   Lrow0 = bx * 64; Lrowmax = NSAMP - 1;
        Sbase = W1; Sstride = 2 * DIM;
        srow_base = by * 16 + wave * 4;             // h rows, max 399
    } else {                          // mat1: hy (+b1)
        mat = 1;
        const int bb = b - 400; kh = bb & 1;
        const int bx = (bb >> 1) & 31, by = bb >> 6;
        Lbase = W1; Lstride = 2 * DIM; Lcol0 = DIM; Lrow0 = by * 64; Lrowmax = HID - 1;
        Sbase = Y;  Sstride = DIM;
        srow_base = bx * 16 + wave * 4;             // n rows, max 511
    }
    const int kc0 = kh * 200;

    // stage lane-dim tile: 64 rows x 200 k -> Ls, coalesced float4
    for (int idx = t; idx < 3200; idx += 256) {
        int row = idx / 50, q = idx % 50;
        int r = Lrow0 + row; if (r > Lrowmax) r = Lrowmax;
        float4 v = *(const float4*)(Lbase + (size_t)r * Lstride + Lcol0 + kc0 + 4 * q);
        *(float4*)(Ls + row * 204 + 4 * q) = v;
    }
    __syncthreads();

    float acc[4] = {0.f, 0.f, 0.f, 0.f};
#pragma unroll 2
    for (int k4 = 0; k4 < 50; k4++) {
        float4 xv = *(const float4*)(Ls + lane * 204 + 4 * k4);
#pragma unroll
        for (int c = 0; c < 4; c++) {
            const float* __restrict__ wp =
                Sbase + (size_t)(srow_base + c) * Sstride + Lcol0 - (mat ? DIM : 0)
                      + (mat ? 0 : 0) + kc0 + 4 * k4;   // uniform base
            // (Scol0 is 0 for both mats; W1x cols 0..400 via kc0, W1y via Lcol0 on L side)
            float4 wv = *(const float4*)(Sbase + (size_t)(srow_base + c) * Sstride + kc0 + 4 * k4);
            (void)wp;
            acc[c] = fmaf(xv.x, wv.x, acc[c]);
            acc[c] = fmaf(xv.y, wv.y, acc[c]);
            acc[c] = fmaf(xv.z, wv.z, acc[c]);
            acc[c] = fmaf(xv.w, wv.w, acc[c]);
        }
    }

    if (mat == 0) {
        // hxT8[h>>3][j][h&7], h = srow_base+c (quad-aligned), j = Lrow0+lane
        const int j = Lrow0 + lane;
        float* __restrict__ base =
            hxT8 + (size_t)(srow_base >> 3) * 4096 + (size_t)j * 8 + (srow_base & 4);
#pragma unroll
        for (int c = 0; c < 4; c++)
            atomicAdd(base + c, acc[c]);
    } else {
        const int h = Lrow0 + lane;
        if (h < HID) {
            if (kh == 0) {
                float bv = b1[h];
#pragma unroll
                for (int c = 0; c < 4; c++) acc[c] += bv;
            }
#pragma unroll
            for (int c = 0; c < 4; c++)
                atomicAdd(hyb + (size_t)(srow_base + c) * HID + h, acc[c]);
        }
    }
}

// ---------------- K2: pair scores, no LDS, no barriers ----------------
// grid (8 jx, 128 iy) = 1024 blocks, 256 thr. lane=j, wave=i (4 i per block).
__global__ __launch_bounds__(256) void club_pair_kernel(
    const float* __restrict__ hxT8, const float* __restrict__ hyb,
    const float* __restrict__ W2, const float* __restrict__ b2,
    double* __restrict__ expsum, double* __restrict__ tsum,
    double* __restrict__ diagT)
{
    const int t    = threadIdx.x;
    const int lane = t & 63;
    const int wave = __builtin_amdgcn_readfirstlane(t >> 6);
    const int jx   = blockIdx.x;
    const int j    = jx * 64 + lane;
    const int i    = blockIdx.y * 4 + wave;     // uniform

    const float* __restrict__ Bp = hxT8 + (size_t)j * 8;   // + g*4096 per group
    const float* __restrict__ Ap = hyb + (size_t)i * HID;

    float acc0 = 0.f, acc1 = 0.f;
#pragma unroll 2
    for (int g = 0; g < 50; g++) {
        const int h = 8 * g;
        float4 b0 = *(const float4*)(Bp + (size_t)g * 4096);      // coalesced dwordx4
        float4 b1v = *(const float4*)(Bp + (size_t)g * 4096 + 4);
        float4 a0 = *(const float4*)(Ap + h);                     // uniform -> s_load
        float4 a1 = *(const float4*)(Ap + h + 4);
        float4 w0 = *(const float4*)(W2 + h);
        float4 w1 = *(const float4*)(W2 + h + 4);
        acc0 = fmaf(fmaxf(a0.x + b0.x, 0.f), w0.x, acc0);
        acc1 = fmaf(fmaxf(a0.y + b0.y, 0.f), w0.y, acc1);
        acc0 = fmaf(fmaxf(a0.z + b0.z, 0.f), w0.z, acc0);
        acc1 = fmaf(fmaxf(a0.w + b0.w, 0.f), w0.w, acc1);
        acc0 = fmaf(fmaxf(a1.x + b1v.x, 0.f), w1.x, acc0);
        acc1 = fmaf(fmaxf(a1.y + b1v.y, 0.f), w1.y, acc1);
        acc0 = fmaf(fmaxf(a1.z + b1v.z, 0.f), w1.z, acc0);
        acc1 = fmaf(fmaxf(a1.w + b1v.w, 0.f), w1.w, acc1);
    }

    // epilogue: softplus + fp64 reduction over the 64 j-lanes
    float s  = (acc0 + acc1) + b2[0];
    float es = expf(s);
    float T  = log1pf(es);               // softplus
    if (j == i) diagT[i] = (double)T;    // T0[i]
    double eD = 1.0 + (double)es;        // exp(softplus(s)) exactly
    double tD = (double)T;
    for (int off = 32; off > 0; off >>= 1) {
        eD += __shfl_down(eD, off);
        tD += __shfl_down(tD, off);
    }
    if (lane == 0) {
        expsum[i * 8 + jx] = eD;
        tsum  [i * 8 + jx] = tD;
    }
}

// ---------------- K3: final assembly ----------------
__global__ __launch_bounds__(512) void club_final_kernel(
    const double* __restrict__ expsum, const double* __restrict__ tsum,
    const double* __restrict__ diagT, float* __restrict__ out)
{
    __shared__ double sh[3 * 512];
    const int t = threadIdx.x;   // = i
    double es = 0.0, ts = 0.0;
#pragma unroll
    for (int b = 0; b < 8; b++) { es += expsum[t * 8 + b]; ts += tsum[t * 8 + b]; }
    sh[t] = log(es); sh[512 + t] = ts; sh[1024 + t] = diagT[t];
    __syncthreads();
    for (int off = 256; off > 0; off >>= 1) {
        if (t < off) {
            sh[t]        += sh[t + off];
            sh[512 + t]  += sh[512 + t + off];
            sh[1024 + t] += sh[1024 + t + off];
        }
        __syncthreads();
    }
    if (t == 0) {
        double t0m  = sh[1024] / 512.0;
        double lsem = sh[0]    / 512.0;
        double t1m  = sh[512]  / (512.0 * 512.0);
        out[0] = (float)(t0m - (lsem - log(512.0)));
        out[1] = (float)(t0m - t1m);
    }
}

extern "C" void kernel_launch(void* const* d_in, const int* in_sizes, int n_in,
                              void* d_out, int out_size, void* d_ws, size_t ws_size,
                              hipStream_t stream) {
    const float* X  = (const float*)d_in[0];
    const float* Y  = (const float*)d_in[1];
    const float* W1 = (const float*)d_in[2];
    const float* b1 = (const float*)d_in[3];
    const float* W2 = (const float*)d_in[4];
    const float* b2 = (const float*)d_in[5];
    float* out = (float*)d_out;

    char* ws = (char*)d_ws;
    float*  hxT8   = (float*) (ws);                 // 50*512*8*4 = 819200
    float*  hyb    = (float*) (ws +  819200);       // 512*400*4  = 819200
    double* expsum = (double*)(ws + 1638400);       // 512*8*8    = 32768
    double* tsum   = (double*)(ws + 1671168);       // 32768
    double* diagT  = (double*)(ws + 1703936);       // 4096

    // zero the atomic-accumulation targets (hxT8 + hyb, contiguous)
    hipMemsetAsync(ws, 0, 1638400, stream);

    club_gemm_kernel <<<dim3(848),    256, 0, stream>>>(X, Y, W1, b1, hxT8, hyb);
    club_pair_kernel <<<dim3(8, 128), 256, 0, stream>>>(hxT8, hyb, W2, b2,
                                                        expsum, tsum, diagT);
    club_final_kernel<<<1, 512, 0, stream>>>(expsum, tsum, diagT, out);
}